// Round 13
// baseline (205.877 us; speedup 1.0000x reference)
//
#include <hip/hip_runtime.h>

#define CIN 64
#define COUT 128
#define BSH 9                   // 512 dsts per coarse bucket
#define NB2 196                 // ceil(100000/512)
#define BCAP 10240              // bucket capacity (avg 8163, >20 sigma pad)
#define CURPAD 16               // bucket cursor padding (one per 64B line)
#define EPB 8192                // edges per scatter block
constexpr float LN_EPS = 1e-5f;

typedef __attribute__((ext_vector_type(8))) short    bf16x8;
typedef __attribute__((ext_vector_type(4))) float    f32x4;
typedef __attribute__((ext_vector_type(8))) unsigned short us8;

__device__ inline float b2f(unsigned short u) {
    union { unsigned int i; float f; } v; v.i = ((unsigned int)u) << 16; return v.f;
}
__device__ inline unsigned short f2b(float f) {
    union { float f; unsigned int i; } v; v.f = f;
    unsigned int x = v.i;
    return (unsigned short)((x + 0x7FFFu + ((x >> 16) & 1u)) >> 16);
}

// ============ fused prep: 2-phase bucket scatter | x->bf16 | weights->fragment-packed ============
// entry = (dst&511)<<17 | src
__global__ __launch_bounds__(256) void fused_prep(
    const int* __restrict__ src, const int* __restrict__ dst,
    const float* __restrict__ x,
    const float* __restrict__ wr0, const float* __restrict__ wn0,
    const float* __restrict__ wr1, const float* __restrict__ wn1,
    const float* __restrict__ wl,
    int* __restrict__ bcur, unsigned int* __restrict__ bstage,
    unsigned short* __restrict__ xb,
    unsigned short* __restrict__ wp0, unsigned short* __restrict__ wp1,
    int n_nodes, int n_edges, int eblk, int cblk)
{
    __shared__ unsigned int  ent[EPB];        // 32 KB
    __shared__ unsigned char ebk[EPB];        // 8 KB
    __shared__ int cnt[NB2], gb[NB2], lcur[NB2];

    const int bid = blockIdx.x;
    const int t = threadIdx.x;
    if (bid < eblk) {
        const int e0 = bid * EPB;
        const int n = min(EPB, n_edges - e0);
        for (int i = t; i < NB2; i += 256) cnt[i] = 0;
        __syncthreads();
        for (int i = t; i < n; i += 256) {
            const int d = dst[e0 + i];
            ent[i] = ((unsigned int)(d & 511) << 17) | (unsigned int)src[e0 + i];
            const int b = d >> BSH;
            ebk[i] = (unsigned char)b;
            atomicAdd(&cnt[b], 1);
        }
        __syncthreads();
        for (int i = t; i < NB2; i += 256) {
            gb[i] = (cnt[i] > 0) ? atomicAdd(&bcur[i * CURPAD], cnt[i]) : 0;
            lcur[i] = 0;
        }
        __syncthreads();
        for (int i = t; i < n; i += 256) {
            const int b = ebk[i];
            const int pos = gb[b] + atomicAdd(&lcur[b], 1);
            if (pos < BCAP) bstage[(size_t)b * BCAP + pos] = ent[i];
        }
    } else if (bid < eblk + cblk) {
        // ---- x (f32) -> xb [npad][64] bf16 ----
        int tt = (bid - eblk) * 256 + t;
        int node = tt >> 4;
        if (node >= n_nodes) return;
        int c = (tt & 15) << 2;
        const float4 v = *reinterpret_cast<const float4*>(x + (size_t)node * CIN + c);
        unsigned int lo = (unsigned int)f2b(v.x) | ((unsigned int)f2b(v.y) << 16);
        unsigned int hi = (unsigned int)f2b(v.z) | ((unsigned int)f2b(v.w) << 16);
        unsigned int* p0 = (unsigned int*)(xb + (size_t)node * 64 + c);
        p0[0] = lo; p0[1] = hi;
    } else {
        // ---- weights -> fragment-packed bf16 ----
        int tt = (bid - eblk - cblk) * 256 + t;
        if (tt < 8 * 4 * 64 * 8) {
            const int j = tt & 7, idx = tt >> 3;
            const int lane = idx & 63, fk = idx >> 6;      // fk = nt*4+ks
            const int nt = fk >> 2, ks = fk & 3;
            const int n = nt * 16 + (lane & 15);
            const int k = ks * 32 + (lane >> 4) * 8 + j;
            const float v = (k < 64) ? wr0[k * COUT + n] : wn0[(k - 64) * COUT + n];
            wp0[tt] = f2b(v);
        } else {
            const int t2 = tt - 8 * 4 * 64 * 8;
            if (t2 >= 8 * 10 * 64 * 8) return;
            const int j = t2 & 7, idx = t2 >> 3;
            const int lane = idx & 63, fk = idx >> 6;      // fk = nt*10+ks
            const int nt = fk / 10, ks = fk % 10;
            const int n = nt * 16 + (lane & 15);
            const int k = ks * 32 + (lane >> 4) * 8 + j;
            float v;
            if (k < 128)      v = wr1[k * COUT + n];
            else if (k < 256) v = wn1[(k - 128) * COUT + n];
            else              v = wl[(k - 256) * COUT + n];
            wp1[t2] = f2b(v);
        }
    }
}

// ============ per-bucket CSR: sort 512-dst bucket in LDS, write back coalesced ============
__global__ __launch_bounds__(256) void bucket_csr(
    unsigned int* __restrict__ bstage,
    const int* __restrict__ bcur,
    int* __restrict__ rowptr, int* __restrict__ deg, int n_nodes)
{
    __shared__ unsigned int ent[BCAP];   // 40 KB
    __shared__ int cnt[512], base[512], lc[512];
    __shared__ int sc[2][512];

    const int b = blockIdx.x;
    const int t = threadIdx.x;
    const int nb = min(bcur[b * CURPAD], BCAP);
    unsigned int* bk = bstage + (size_t)b * BCAP;

    for (int i = t; i < 512; i += 256) cnt[i] = 0;
    __syncthreads();
    for (int i = t; i < nb; i += 256) {
        const unsigned int p = bk[i];
        ent[i] = p;
        atomicAdd(&cnt[p >> 17], 1);
    }
    __syncthreads();
    for (int i = t; i < 512; i += 256) sc[0][i] = cnt[i];
    __syncthreads();
    int pin = 0;
#pragma unroll
    for (int off = 1; off < 512; off <<= 1) {
        for (int i = t; i < 512; i += 256) {
            int v = sc[pin][i];
            if (i >= off) v += sc[pin][i - off];
            sc[pin ^ 1][i] = v;
        }
        __syncthreads();
        pin ^= 1;
    }
    for (int i = t; i < 512; i += 256) {
        const int bs = sc[pin][i] - cnt[i];
        base[i] = bs; lc[i] = 0;
        const int d = (b << BSH) + i;
        if (d < n_nodes) { rowptr[d] = b * BCAP + bs; deg[d] = cnt[i]; }
    }
    __syncthreads();
    __shared__ unsigned int sorted[BCAP];  // 40 KB
    for (int i = t; i < nb; i += 256) {
        const unsigned int p = ent[i];
        const int dl = p >> 17;
        const int pos = base[dl] + atomicAdd(&lc[dl], 1);
        sorted[pos] = p & 0x1FFFFu;
    }
    __syncthreads();
    for (int i = t; i < nb; i += 256) bk[i] = sorted[i];
}

// ================= fused conv0: gather agg0 -> LDS (9.2 KB) + MFMA + LN + ReLU =================
// D[m][n]: col = lane&15, row = (lane>>4)*4 + reg  (m89-verified)
__global__ __launch_bounds__(256) void fused_conv0(
    const unsigned short* __restrict__ X,   // xb [npad][64]
    const int* __restrict__ rowptr, const int* __restrict__ deg,
    const unsigned int* __restrict__ es,
    const unsigned short* __restrict__ Wpk, // wp0 [8][4][64][8]
    const float* __restrict__ b, const float* __restrict__ gamma,
    const float* __restrict__ beta,
    unsigned short* __restrict__ Y,         // yb [npad][128]
    int n_nodes)
{
    __shared__ unsigned short agg[64][72];  // 9216 B
    const int tid = threadIdx.x;
    const int lane = tid & 63;
    const int node0 = blockIdx.x * 64;
    const int fr = lane & 15;
    const int gbase = lane & 48;

    // ---- phase A: gather agg0 for 64 nodes (16 lanes/node, 4ch/lane, r12 order) ----
#pragma unroll
    for (int p = 0; p < 4; p++) {
        const int nl = p * 16 + (tid >> 4);
        const int node = node0 + nl;
        const bool ok = (node < n_nodes);
        const int start = ok ? rowptr[node] : 0;
        const int len = ok ? deg[node] : 0;
        float a0 = 0.f, a1v = 0.f, a2 = 0.f, a3 = 0.f;
        for (int k0 = 0; k0 < len; k0 += 16) {
            const int m = min(16, len - k0);
            const int my = (fr < m) ? (int)es[start + k0 + fr] : 0;
            int j = 0;
            for (; j + 3 < m; j += 4) {
                const int s0 = __shfl(my, gbase + j);
                const int s1 = __shfl(my, gbase + j + 1);
                const int s2 = __shfl(my, gbase + j + 2);
                const int s3 = __shfl(my, gbase + j + 3);
                const unsigned long long u0 =
                    *(const unsigned long long*)(X + (size_t)s0 * 64 + fr * 4);
                const unsigned long long u1 =
                    *(const unsigned long long*)(X + (size_t)s1 * 64 + fr * 4);
                const unsigned long long u2 =
                    *(const unsigned long long*)(X + (size_t)s2 * 64 + fr * 4);
                const unsigned long long u3 =
                    *(const unsigned long long*)(X + (size_t)s3 * 64 + fr * 4);
                a0  += b2f((unsigned short)u0) + b2f((unsigned short)u1)
                     + b2f((unsigned short)u2) + b2f((unsigned short)u3);
                a1v += b2f((unsigned short)(u0 >> 16)) + b2f((unsigned short)(u1 >> 16))
                     + b2f((unsigned short)(u2 >> 16)) + b2f((unsigned short)(u3 >> 16));
                a2  += b2f((unsigned short)(u0 >> 32)) + b2f((unsigned short)(u1 >> 32))
                     + b2f((unsigned short)(u2 >> 32)) + b2f((unsigned short)(u3 >> 32));
                a3  += b2f((unsigned short)(u0 >> 48)) + b2f((unsigned short)(u1 >> 48))
                     + b2f((unsigned short)(u2 >> 48)) + b2f((unsigned short)(u3 >> 48));
            }
            for (; j < m; j++) {
                const int s0 = __shfl(my, gbase + j);
                const unsigned long long u0 =
                    *(const unsigned long long*)(X + (size_t)s0 * 64 + fr * 4);
                a0  += b2f((unsigned short)u0);
                a1v += b2f((unsigned short)(u0 >> 16));
                a2  += b2f((unsigned short)(u0 >> 32));
                a3  += b2f((unsigned short)(u0 >> 48));
            }
        }
        const unsigned long long pk = (unsigned long long)f2b(a0)
            | ((unsigned long long)f2b(a1v) << 16)
            | ((unsigned long long)f2b(a2)  << 32)
            | ((unsigned long long)f2b(a3)  << 48);
        *(unsigned long long*)(&agg[nl][fr * 4]) = pk;
    }
    __syncthreads();

    // ---- phase B: MFMA + LN + ReLU, direct bf16 stores ----
    const int wid = tid >> 6;
    const int m0 = node0 + wid * 16;
    if (m0 >= n_nodes) return;
    const int g = lane >> 4;

    const bf16x8* Xp = reinterpret_cast<const bf16x8*>(X + (size_t)(m0 + fr) * 64) + g;
    bf16x8 a[4];
    a[0] = Xp[0];                                                           // x k 0:32
    a[1] = Xp[4];                                                           // x k 32:64
    a[2] = *reinterpret_cast<const bf16x8*>(&agg[wid * 16 + fr][g * 8]);    // agg k 0:32
    a[3] = *reinterpret_cast<const bf16x8*>(&agg[wid * 16 + fr][32 + g * 8]);

    f32x4 acc[8];
    float gm[8], bt[8];
#pragma unroll
    for (int nt = 0; nt < 8; nt++) {
        const int col = nt * 16 + fr;
        const float bb = b[col];
        acc[nt] = (f32x4){bb, bb, bb, bb};
        gm[nt] = gamma[col]; bt[nt] = beta[col];
    }

    const bf16x8* Wp = reinterpret_cast<const bf16x8*>(Wpk) + lane;
#pragma unroll
    for (int nt = 0; nt < 8; nt++) {
        bf16x8 w[4];
#pragma unroll
        for (int ks = 0; ks < 4; ks++) w[ks] = Wp[(nt * 4 + ks) * 64];
#pragma unroll
        for (int ks = 0; ks < 4; ks++)
            acc[nt] = __builtin_amdgcn_mfma_f32_16x16x32_bf16(a[ks], w[ks], acc[nt], 0, 0, 0);
    }

#pragma unroll
    for (int r = 0; r < 4; r++) {
        float s = 0.f, s2 = 0.f;
#pragma unroll
        for (int nt = 0; nt < 8; nt++) { const float v = acc[nt][r]; s += v; s2 += v * v; }
#pragma unroll
        for (int off = 1; off < 16; off <<= 1) {
            s += __shfl_xor(s, off); s2 += __shfl_xor(s2, off);
        }
        const float mu = s * (1.0f / COUT);
        const float var = s2 * (1.0f / COUT) - mu * mu;
        const float rstd = rsqrtf(var + LN_EPS);
        const int orow = m0 + g * 4 + r;
        if (orow < n_nodes) {
            unsigned short* yp = Y + (size_t)orow * 128 + fr;
#pragma unroll
            for (int nt = 0; nt < 8; nt++) {
                const float v = fmaxf((acc[nt][r] - mu) * rstd * gm[nt] + bt[nt], 0.0f);
                yp[nt * 16] = f2b(v);
            }
        }
    }
}

// ================= fused conv1: gather agg1 -> LDS (17.4 KB) + MFMA + residual + LN + ReLU =================
__global__ __launch_bounds__(256) void fused_conv1(
    const unsigned short* __restrict__ Y,   // yb [npad][128]
    const unsigned short* __restrict__ X,   // xb [npad][64]
    const int* __restrict__ rowptr, const int* __restrict__ deg,
    const unsigned int* __restrict__ es,
    const unsigned short* __restrict__ Wpk, // wp1 [8][10][64][8]
    const float* __restrict__ b1, const float* __restrict__ bl,
    const float* __restrict__ gamma, const float* __restrict__ beta,
    float* __restrict__ Out, int n_nodes)
{
    __shared__ unsigned short agg[64][136]; // 17408 B
    const int tid = threadIdx.x;
    const int lane = tid & 63;
    const int node0 = blockIdx.x * 64;
    const int fr = lane & 15;
    const int gbase = lane & 48;

    // ---- phase A: gather agg1 for 64 nodes (16 lanes/node, 8ch/lane, r12 order) ----
#pragma unroll
    for (int p = 0; p < 4; p++) {
        const int nl = p * 16 + (tid >> 4);
        const int node = node0 + nl;
        const bool ok = (node < n_nodes);
        const int start = ok ? rowptr[node] : 0;
        const int len = ok ? deg[node] : 0;
        float acc[8] = {0.f, 0.f, 0.f, 0.f, 0.f, 0.f, 0.f, 0.f};
        for (int k0 = 0; k0 < len; k0 += 16) {
            const int m = min(16, len - k0);
            const int my = (fr < m) ? (int)es[start + k0 + fr] : 0;
            int j = 0;
            for (; j + 3 < m; j += 4) {
                const int s0 = __shfl(my, gbase + j);
                const int s1 = __shfl(my, gbase + j + 1);
                const int s2 = __shfl(my, gbase + j + 2);
                const int s3 = __shfl(my, gbase + j + 3);
                const us8 r0 = *(const us8*)(Y + (size_t)s0 * 128 + fr * 8);
                const us8 r1 = *(const us8*)(Y + (size_t)s1 * 128 + fr * 8);
                const us8 r2 = *(const us8*)(Y + (size_t)s2 * 128 + fr * 8);
                const us8 r3 = *(const us8*)(Y + (size_t)s3 * 128 + fr * 8);
#pragma unroll
                for (int q = 0; q < 8; q++)
                    acc[q] += b2f(r0[q]) + b2f(r1[q]) + b2f(r2[q]) + b2f(r3[q]);
            }
            for (; j < m; j++) {
                const int s0 = __shfl(my, gbase + j);
                const us8 r0 = *(const us8*)(Y + (size_t)s0 * 128 + fr * 8);
#pragma unroll
                for (int q = 0; q < 8; q++) acc[q] += b2f(r0[q]);
            }
        }
        us8 pk;
#pragma unroll
        for (int q = 0; q < 8; q++) pk[q] = f2b(acc[q]);
        *reinterpret_cast<us8*>(&agg[nl][fr * 8]) = pk;
    }
    __syncthreads();

    // ---- phase B: MFMA + residual + LN + ReLU, direct NT f32 stores ----
    const int wid = tid >> 6;
    const int m0 = node0 + wid * 16;
    if (m0 >= n_nodes) return;
    const int g = lane >> 4;

    const bf16x8* Yp = reinterpret_cast<const bf16x8*>(Y + (size_t)(m0 + fr) * 128) + g;
    const bf16x8* Xp = reinterpret_cast<const bf16x8*>(X + (size_t)(m0 + fr) * 64) + g;
    bf16x8 a[10];
#pragma unroll
    for (int ks = 0; ks < 4; ks++) a[ks] = Yp[ks * 4];                      // y k 0:128
#pragma unroll
    for (int ks = 0; ks < 4; ks++)
        a[4 + ks] = *reinterpret_cast<const bf16x8*>(&agg[wid * 16 + fr][ks * 32 + g * 8]);
    a[8] = Xp[0];                                                           // x k 0:32
    a[9] = Xp[4];                                                           // x k 32:64

    f32x4 acc[8];
    float gm[8], bt[8];
#pragma unroll
    for (int nt = 0; nt < 8; nt++) {
        const int col = nt * 16 + fr;
        const float bb = b1[col] + bl[col];
        acc[nt] = (f32x4){bb, bb, bb, bb};
        gm[nt] = gamma[col]; bt[nt] = beta[col];
    }

    const bf16x8* Wp = reinterpret_cast<const bf16x8*>(Wpk) + lane;
#pragma unroll
    for (int nt = 0; nt < 8; nt++) {
        bf16x8 w[10];
#pragma unroll
        for (int ks = 0; ks < 10; ks++) w[ks] = Wp[(nt * 10 + ks) * 64];
#pragma unroll
        for (int ks = 0; ks < 10; ks++)
            acc[nt] = __builtin_amdgcn_mfma_f32_16x16x32_bf16(a[ks], w[ks], acc[nt], 0, 0, 0);
    }

#pragma unroll
    for (int r = 0; r < 4; r++) {
        float s = 0.f, s2 = 0.f;
#pragma unroll
        for (int nt = 0; nt < 8; nt++) { const float v = acc[nt][r]; s += v; s2 += v * v; }
#pragma unroll
        for (int off = 1; off < 16; off <<= 1) {
            s += __shfl_xor(s, off); s2 += __shfl_xor(s2, off);
        }
        const float mu = s * (1.0f / COUT);
        const float var = s2 * (1.0f / COUT) - mu * mu;
        const float rstd = rsqrtf(var + LN_EPS);
        const int orow = m0 + g * 4 + r;
        if (orow < n_nodes) {
            float* op = Out + (size_t)orow * 128 + fr;
#pragma unroll
            for (int nt = 0; nt < 8; nt++) {
                const float v = fmaxf((acc[nt][r] - mu) * rstd * gm[nt] + bt[nt], 0.0f);
                __builtin_nontemporal_store(v, op + nt * 16);
            }
        }
    }
}

extern "C" void kernel_launch(void* const* d_in, const int* in_sizes, int n_in,
                              void* d_out, int out_size, void* d_ws, size_t ws_size,
                              hipStream_t stream)
{
    const float* x       = (const float*)d_in[0];
    const int*   ei      = (const int*)d_in[1];
    const float* w_root0 = (const float*)d_in[2];
    const float* w_nbr0  = (const float*)d_in[3];
    const float* b0      = (const float*)d_in[4];
    const float* w_root1 = (const float*)d_in[5];
    const float* w_nbr1  = (const float*)d_in[6];
    const float* b1      = (const float*)d_in[7];
    const float* gamma0  = (const float*)d_in[8];
    const float* beta0   = (const float*)d_in[9];
    const float* gamma1  = (const float*)d_in[10];
    const float* beta1   = (const float*)d_in[11];
    const float* w_lin   = (const float*)d_in[12];
    const float* b_lin   = (const float*)d_in[13];
    float* out = (float*)d_out;

    const int n_nodes = in_sizes[0] / CIN;   // 100000
    const int n_edges = in_sizes[1] / 2;     // 1600000
    const int* src = ei;
    const int* dst = ei + n_edges;
    const int npad = (n_nodes + 63) & ~63;
    const int nbuck = (n_nodes + (1 << BSH) - 1) >> BSH;  // 196

    // ---- workspace layout ----
    char* ws = (char*)d_ws;
    unsigned short* xb  = (unsigned short*)ws;                       // npad*64 bf16
    unsigned short* yb  = xb + (size_t)npad * 64;                    // npad*128 bf16
    unsigned short* wp0 = yb + (size_t)npad * 128;                   // 16384
    unsigned short* wp1 = wp0 + 8 * 4 * 64 * 8;                      // 40960
    int*  bcur   = (int*)(wp1 + 8 * 10 * 64 * 8);                    // nbuck*CURPAD
    int*  rowptr = bcur + (size_t)nbuck * CURPAD;                    // n_nodes
    int*  deg    = rowptr + n_nodes;                                 // n_nodes
    unsigned int* bstage = (unsigned int*)(deg + n_nodes);           // nbuck*BCAP (es)

    const int eblk = (n_edges + EPB - 1) / EPB;                      // 196
    const int cblk = (n_nodes * 16 + 255) / 256;
    const int wblk = (8 * 4 * 64 * 8 + 8 * 10 * 64 * 8 + 255) / 256;
    const int nblk64 = npad / 64;

    // ---- prep: 2-phase bucket scatter | x convert | weight pack ----
    hipMemsetAsync(bcur, 0, (size_t)nbuck * CURPAD * sizeof(int), stream);
    fused_prep<<<eblk + cblk + wblk, 256, 0, stream>>>(
        src, dst, x, w_root0, w_nbr0, w_root1, w_nbr1, w_lin,
        bcur, bstage, xb, wp0, wp1, n_nodes, n_edges, eblk, cblk);
    bucket_csr<<<nbuck, 256, 0, stream>>>(bstage, bcur, rowptr, deg, n_nodes);

    // ---- GraphConv 0 (gather + conv fused, slim LDS) ----
    fused_conv0<<<nblk64, 256, 0, stream>>>(xb, rowptr, deg, bstage, wp0,
                                            b0, gamma0, beta0, yb, n_nodes);

    // ---- GraphConv 1 + residual (gather + conv fused, slim LDS) ----
    fused_conv1<<<nblk64, 256, 0, stream>>>(yb, xb, rowptr, deg, bstage, wp1,
                                            b1, b_lin, gamma1, beta1, out, n_nodes);
}

// Round 14
// 189.084 us; speedup vs baseline: 1.0888x; 1.0888x over previous
//
#include <hip/hip_runtime.h>

#define CIN 64
#define COUT 128
#define BSH 9                   // 512 dsts per coarse bucket
#define NB2 196                 // ceil(100000/512)
#define BCAP 10240              // bucket capacity (avg 8163, >20 sigma pad)
#define CURPAD 16               // bucket cursor padding (one per 64B line)
#define EPB 8192                // edges per scatter block
constexpr float LN_EPS = 1e-5f;

typedef __attribute__((ext_vector_type(8))) short    bf16x8;
typedef __attribute__((ext_vector_type(4))) float    f32x4;
typedef __attribute__((ext_vector_type(8))) unsigned short us8;

__device__ inline float b2f(unsigned short u) {
    union { unsigned int i; float f; } v; v.i = ((unsigned int)u) << 16; return v.f;
}
__device__ inline unsigned short f2b(float f) {
    union { float f; unsigned int i; } v; v.f = f;
    unsigned int x = v.i;
    return (unsigned short)((x + 0x7FFFu + ((x >> 16) & 1u)) >> 16);
}

// ============ fused prep: 2-phase bucket scatter | x->bf16 | weights->fragment-packed ============
// entry = (dst&511)<<17 | src  (src<2^17, 26 bits total)
__global__ __launch_bounds__(256) void fused_prep(
    const int* __restrict__ src, const int* __restrict__ dst,
    const float* __restrict__ x,
    const float* __restrict__ wr0, const float* __restrict__ wn0,
    const float* __restrict__ wr1, const float* __restrict__ wn1,
    const float* __restrict__ wl,
    int* __restrict__ bcur, unsigned int* __restrict__ bstage,
    unsigned short* __restrict__ ab0, unsigned short* __restrict__ a1,
    unsigned short* __restrict__ wp0, unsigned short* __restrict__ wp1,
    int n_nodes, int n_edges, int eblk, int cblk)
{
    __shared__ unsigned int  ent[EPB];        // 32 KB
    __shared__ unsigned char ebk[EPB];        // 8 KB
    __shared__ int cnt[NB2], gb[NB2], lcur[NB2];

    const int bid = blockIdx.x;
    const int t = threadIdx.x;
    if (bid < eblk) {
        // ---- phase 1: stage + count ----
        const int e0 = bid * EPB;
        const int n = min(EPB, n_edges - e0);
        for (int i = t; i < NB2; i += 256) cnt[i] = 0;
        __syncthreads();
        for (int i = t; i < n; i += 256) {
            const int d = dst[e0 + i];
            ent[i] = ((unsigned int)(d & 511) << 17) | (unsigned int)src[e0 + i];
            const int b = d >> BSH;
            ebk[i] = (unsigned char)b;
            atomicAdd(&cnt[b], 1);
        }
        __syncthreads();
        // ---- reserve block-exclusive ranges (1 global atomic per bucket) ----
        for (int i = t; i < NB2; i += 256) {
            gb[i] = (cnt[i] > 0) ? atomicAdd(&bcur[i * CURPAD], cnt[i]) : 0;
            lcur[i] = 0;
        }
        __syncthreads();
        // ---- phase 2: write runs (contiguous per bucket per block) ----
        for (int i = t; i < n; i += 256) {
            const int b = ebk[i];
            const int pos = gb[b] + atomicAdd(&lcur[b], 1);
            if (pos < BCAP) bstage[(size_t)b * BCAP + pos] = ent[i];
        }
    } else if (bid < eblk + cblk) {
        // ---- x (f32) -> ab0[:,0:64] and a1[:,256:320] bf16 ----
        int tt = (bid - eblk) * 256 + t;
        int node = tt >> 4;
        if (node >= n_nodes) return;
        int c = (tt & 15) << 2;
        const float4 v = *reinterpret_cast<const float4*>(x + (size_t)node * CIN + c);
        unsigned int lo = (unsigned int)f2b(v.x) | ((unsigned int)f2b(v.y) << 16);
        unsigned int hi = (unsigned int)f2b(v.z) | ((unsigned int)f2b(v.w) << 16);
        unsigned int* p0 = (unsigned int*)(ab0 + (size_t)node * 128 + c);
        p0[0] = lo; p0[1] = hi;
        unsigned int* p1 = (unsigned int*)(a1 + (size_t)node * 320 + 256 + c);
        p1[0] = lo; p1[1] = hi;
    } else {
        // ---- weights -> fragment-packed bf16 ----
        int tt = (bid - eblk - cblk) * 256 + t;
        if (tt < 8 * 4 * 64 * 8) {
            const int j = tt & 7, idx = tt >> 3;
            const int lane = idx & 63, fk = idx >> 6;      // fk = nt*4+ks
            const int nt = fk >> 2, ks = fk & 3;
            const int n = nt * 16 + (lane & 15);
            const int k = ks * 32 + (lane >> 4) * 8 + j;
            const float v = (k < 64) ? wr0[k * COUT + n] : wn0[(k - 64) * COUT + n];
            wp0[tt] = f2b(v);
        } else {
            const int t2 = tt - 8 * 4 * 64 * 8;
            if (t2 >= 8 * 10 * 64 * 8) return;
            const int j = t2 & 7, idx = t2 >> 3;
            const int lane = idx & 63, fk = idx >> 6;      // fk = nt*10+ks
            const int nt = fk / 10, ks = fk % 10;
            const int n = nt * 16 + (lane & 15);
            const int k = ks * 32 + (lane >> 4) * 8 + j;
            float v;
            if (k < 128)      v = wr1[k * COUT + n];
            else if (k < 256) v = wn1[(k - 128) * COUT + n];
            else              v = wl[(k - 256) * COUT + n];
            wp1[t2] = f2b(v);
        }
    }
}

// ============ per-bucket CSR: sort 512-dst bucket in LDS, write back coalesced ============
__global__ __launch_bounds__(256) void bucket_csr(
    unsigned int* __restrict__ bstage,   // in-place: becomes sorted src list
    const int* __restrict__ bcur,
    int* __restrict__ rowptr, int* __restrict__ deg, int n_nodes)
{
    __shared__ unsigned int ent[BCAP];   // 40 KB
    __shared__ int cnt[512], base[512], lc[512];
    __shared__ int sc[2][512];

    const int b = blockIdx.x;
    const int t = threadIdx.x;
    const int nb = min(bcur[b * CURPAD], BCAP);
    unsigned int* bk = bstage + (size_t)b * BCAP;

    for (int i = t; i < 512; i += 256) cnt[i] = 0;
    __syncthreads();
    for (int i = t; i < nb; i += 256) {
        const unsigned int p = bk[i];
        ent[i] = p;
        atomicAdd(&cnt[p >> 17], 1);
    }
    __syncthreads();
    // inclusive scan of cnt[512] (Hillis-Steele, double-buffered)
    for (int i = t; i < 512; i += 256) sc[0][i] = cnt[i];
    __syncthreads();
    int pin = 0;
#pragma unroll
    for (int off = 1; off < 512; off <<= 1) {
        for (int i = t; i < 512; i += 256) {
            int v = sc[pin][i];
            if (i >= off) v += sc[pin][i - off];
            sc[pin ^ 1][i] = v;
        }
        __syncthreads();
        pin ^= 1;
    }
    for (int i = t; i < 512; i += 256) {
        const int bs = sc[pin][i] - cnt[i];
        base[i] = bs; lc[i] = 0;
        const int d = (b << BSH) + i;
        if (d < n_nodes) { rowptr[d] = b * BCAP + bs; deg[d] = cnt[i]; }
    }
    __syncthreads();
    // permute into sorted order
    __shared__ unsigned int sorted[BCAP];  // 40 KB
    for (int i = t; i < nb; i += 256) {
        const unsigned int p = ent[i];
        const int dl = p >> 17;
        const int pos = base[dl] + atomicAdd(&lc[dl], 1);
        sorted[pos] = p & 0x1FFFFu;
    }
    __syncthreads();
    for (int i = t; i < nb; i += 256) bk[i] = sorted[i];   // coalesced write-back
}

// ================= gathers: dense edge list, shfl-broadcast, 4-deep MLP =================

__global__ __launch_bounds__(256) void gather_c64(
    unsigned short* __restrict__ ab0, const int* __restrict__ rowptr,
    const int* __restrict__ deg, const unsigned int* __restrict__ es, int n_nodes)
{
    const int node = blockIdx.x * 16 + (threadIdx.x >> 4);
    if (node >= n_nodes) return;
    const int lane = threadIdx.x & 63;
    const int fr = lane & 15;
    const int gbase = lane & 48;
    const int start = rowptr[node];
    const int len = deg[node];
    float a0 = 0.f, a1v = 0.f, a2 = 0.f, a3 = 0.f;

    for (int k0 = 0; k0 < len; k0 += 16) {
        const int m = min(16, len - k0);
        const int my = (fr < m) ? (int)es[start + k0 + fr] : 0;
        int j = 0;
        for (; j + 3 < m; j += 4) {
            const int s0 = __shfl(my, gbase + j);
            const int s1 = __shfl(my, gbase + j + 1);
            const int s2 = __shfl(my, gbase + j + 2);
            const int s3 = __shfl(my, gbase + j + 3);
            const unsigned long long u0 =
                *(const unsigned long long*)(ab0 + (size_t)s0 * 128 + fr * 4);
            const unsigned long long u1 =
                *(const unsigned long long*)(ab0 + (size_t)s1 * 128 + fr * 4);
            const unsigned long long u2 =
                *(const unsigned long long*)(ab0 + (size_t)s2 * 128 + fr * 4);
            const unsigned long long u3 =
                *(const unsigned long long*)(ab0 + (size_t)s3 * 128 + fr * 4);
            a0  += b2f((unsigned short)u0) + b2f((unsigned short)u1)
                 + b2f((unsigned short)u2) + b2f((unsigned short)u3);
            a1v += b2f((unsigned short)(u0 >> 16)) + b2f((unsigned short)(u1 >> 16))
                 + b2f((unsigned short)(u2 >> 16)) + b2f((unsigned short)(u3 >> 16));
            a2  += b2f((unsigned short)(u0 >> 32)) + b2f((unsigned short)(u1 >> 32))
                 + b2f((unsigned short)(u2 >> 32)) + b2f((unsigned short)(u3 >> 32));
            a3  += b2f((unsigned short)(u0 >> 48)) + b2f((unsigned short)(u1 >> 48))
                 + b2f((unsigned short)(u2 >> 48)) + b2f((unsigned short)(u3 >> 48));
        }
        for (; j < m; j++) {
            const int s0 = __shfl(my, gbase + j);
            const unsigned long long u0 =
                *(const unsigned long long*)(ab0 + (size_t)s0 * 128 + fr * 4);
            a0  += b2f((unsigned short)u0);
            a1v += b2f((unsigned short)(u0 >> 16));
            a2  += b2f((unsigned short)(u0 >> 32));
            a3  += b2f((unsigned short)(u0 >> 48));
        }
    }
    const unsigned long long p = (unsigned long long)f2b(a0)
        | ((unsigned long long)f2b(a1v) << 16)
        | ((unsigned long long)f2b(a2)  << 32)
        | ((unsigned long long)f2b(a3)  << 48);
    *(unsigned long long*)(ab0 + (size_t)node * 128 + 64 + fr * 4) = p;
}

__global__ __launch_bounds__(256) void gather_c128(
    unsigned short* __restrict__ a1, const int* __restrict__ rowptr,
    const int* __restrict__ deg, const unsigned int* __restrict__ es, int n_nodes)
{
    const int node = blockIdx.x * 16 + (threadIdx.x >> 4);
    if (node >= n_nodes) return;
    const int lane = threadIdx.x & 63;
    const int fr = lane & 15;
    const int gbase = lane & 48;
    const int start = rowptr[node];
    const int len = deg[node];
    float acc[8] = {0.f, 0.f, 0.f, 0.f, 0.f, 0.f, 0.f, 0.f};

    for (int k0 = 0; k0 < len; k0 += 16) {
        const int m = min(16, len - k0);
        const int my = (fr < m) ? (int)es[start + k0 + fr] : 0;
        int j = 0;
        for (; j + 3 < m; j += 4) {
            const int s0 = __shfl(my, gbase + j);
            const int s1 = __shfl(my, gbase + j + 1);
            const int s2 = __shfl(my, gbase + j + 2);
            const int s3 = __shfl(my, gbase + j + 3);
            const us8 r0 = *(const us8*)(a1 + (size_t)s0 * 320 + fr * 8);
            const us8 r1 = *(const us8*)(a1 + (size_t)s1 * 320 + fr * 8);
            const us8 r2 = *(const us8*)(a1 + (size_t)s2 * 320 + fr * 8);
            const us8 r3 = *(const us8*)(a1 + (size_t)s3 * 320 + fr * 8);
#pragma unroll
            for (int q = 0; q < 8; q++)
                acc[q] += b2f(r0[q]) + b2f(r1[q]) + b2f(r2[q]) + b2f(r3[q]);
        }
        for (; j < m; j++) {
            const int s0 = __shfl(my, gbase + j);
            const us8 r0 = *(const us8*)(a1 + (size_t)s0 * 320 + fr * 8);
#pragma unroll
            for (int q = 0; q < 8; q++) acc[q] += b2f(r0[q]);
        }
    }
    us8 p;
#pragma unroll
    for (int q = 0; q < 8; q++) p[q] = f2b(acc[q]);
    *(us8*)(a1 + (size_t)node * 320 + 128 + fr * 8) = p;
}

// ================= MFMA convs (fragment-packed W, preloaded A, no-LDS epilogue) =================
// D[m][n]: col = lane&15, row = (lane>>4)*4 + reg  (m89-verified)

__global__ __launch_bounds__(256) void conv0_mfma(
    const unsigned short* __restrict__ A,   // ab0 [npad][128]
    const unsigned short* __restrict__ Wpk, // wp0 [8][4][64][8]
    const float* __restrict__ b, const float* __restrict__ gamma,
    const float* __restrict__ beta,
    unsigned short* __restrict__ Yout,      // a1 base [npad][320], y at cols 0:128
    int n_nodes)
{
    const int wid = threadIdx.x >> 6;
    const int lane = threadIdx.x & 63;
    const int m0 = blockIdx.x * 64 + wid * 16;
    if (m0 >= n_nodes) return;
    const int g = lane >> 4, fr = lane & 15;

    const bf16x8* Ap = reinterpret_cast<const bf16x8*>(A + (size_t)(m0 + fr) * 128) + g;
    bf16x8 a[4];
#pragma unroll
    for (int ks = 0; ks < 4; ks++) a[ks] = Ap[ks * 4];

    f32x4 acc[8];
    float gm[8], bt[8];
#pragma unroll
    for (int nt = 0; nt < 8; nt++) {
        const int col = nt * 16 + fr;
        const float bb = b[col];
        acc[nt] = (f32x4){bb, bb, bb, bb};
        gm[nt] = gamma[col]; bt[nt] = beta[col];
    }

    const bf16x8* Wp = reinterpret_cast<const bf16x8*>(Wpk) + lane;  // +64 per frag
#pragma unroll
    for (int nt = 0; nt < 8; nt++) {
        bf16x8 w[4];
#pragma unroll
        for (int ks = 0; ks < 4; ks++) w[ks] = Wp[(nt * 4 + ks) * 64];
#pragma unroll
        for (int ks = 0; ks < 4; ks++)
            acc[nt] = __builtin_amdgcn_mfma_f32_16x16x32_bf16(a[ks], w[ks], acc[nt], 0, 0, 0);
    }

    // LN + ReLU + direct bf16 stores (32B runs per 16-lane group; a1 rows L2-resident)
#pragma unroll
    for (int r = 0; r < 4; r++) {
        float s = 0.f, s2 = 0.f;
#pragma unroll
        for (int nt = 0; nt < 8; nt++) { const float v = acc[nt][r]; s += v; s2 += v * v; }
#pragma unroll
        for (int off = 1; off < 16; off <<= 1) {
            s += __shfl_xor(s, off); s2 += __shfl_xor(s2, off);
        }
        const float mu = s * (1.0f / COUT);
        const float var = s2 * (1.0f / COUT) - mu * mu;
        const float rstd = rsqrtf(var + LN_EPS);
        const int orow = m0 + g * 4 + r;
        if (orow < n_nodes) {
            unsigned short* yp = Yout + (size_t)orow * 320 + fr;
#pragma unroll
            for (int nt = 0; nt < 8; nt++) {
                const float v = fmaxf((acc[nt][r] - mu) * rstd * gm[nt] + bt[nt], 0.0f);
                yp[nt * 16] = f2b(v);
            }
        }
    }
}

__global__ __launch_bounds__(256) void conv1_mfma(
    const unsigned short* __restrict__ A,   // a1 [npad][320]
    const unsigned short* __restrict__ Wpk, // wp1 [8][10][64][8]
    const float* __restrict__ b1, const float* __restrict__ bl,
    const float* __restrict__ gamma, const float* __restrict__ beta,
    float* __restrict__ Out, int n_nodes)
{
    const int wid = threadIdx.x >> 6;
    const int lane = threadIdx.x & 63;
    const int m0 = blockIdx.x * 64 + wid * 16;
    if (m0 >= n_nodes) return;
    const int g = lane >> 4, fr = lane & 15;

    const bf16x8* Ap = reinterpret_cast<const bf16x8*>(A + (size_t)(m0 + fr) * 320) + g;
    bf16x8 a[10];
#pragma unroll
    for (int ks = 0; ks < 10; ks++) a[ks] = Ap[ks * 4];

    f32x4 acc[8];
    float gm[8], bt[8];
#pragma unroll
    for (int nt = 0; nt < 8; nt++) {
        const int col = nt * 16 + fr;
        const float bb = b1[col] + bl[col];
        acc[nt] = (f32x4){bb, bb, bb, bb};
        gm[nt] = gamma[col]; bt[nt] = beta[col];
    }

    const bf16x8* Wp = reinterpret_cast<const bf16x8*>(Wpk) + lane;  // +64 per frag
#pragma unroll
    for (int nt = 0; nt < 8; nt++) {
        bf16x8 w[10];
#pragma unroll
        for (int ks = 0; ks < 10; ks++) w[ks] = Wp[(nt * 10 + ks) * 64];
#pragma unroll
        for (int ks = 0; ks < 10; ks++)
            acc[nt] = __builtin_amdgcn_mfma_f32_16x16x32_bf16(a[ks], w[ks], acc[nt], 0, 0, 0);
    }

    // LN + ReLU + direct NT store (no LDS): per (nt,r) a wave writes 4x64B runs
#pragma unroll
    for (int r = 0; r < 4; r++) {
        float s = 0.f, s2 = 0.f;
#pragma unroll
        for (int nt = 0; nt < 8; nt++) { const float v = acc[nt][r]; s += v; s2 += v * v; }
#pragma unroll
        for (int off = 1; off < 16; off <<= 1) {
            s += __shfl_xor(s, off); s2 += __shfl_xor(s2, off);
        }
        const float mu = s * (1.0f / COUT);
        const float var = s2 * (1.0f / COUT) - mu * mu;
        const float rstd = rsqrtf(var + LN_EPS);
        const int orow = m0 + g * 4 + r;
        if (orow < n_nodes) {
            float* op = Out + (size_t)orow * 128 + fr;
#pragma unroll
            for (int nt = 0; nt < 8; nt++) {
                const float v = fmaxf((acc[nt][r] - mu) * rstd * gm[nt] + bt[nt], 0.0f);
                __builtin_nontemporal_store(v, op + nt * 16);
            }
        }
    }
}

extern "C" void kernel_launch(void* const* d_in, const int* in_sizes, int n_in,
                              void* d_out, int out_size, void* d_ws, size_t ws_size,
                              hipStream_t stream)
{
    const float* x       = (const float*)d_in[0];
    const int*   ei      = (const int*)d_in[1];
    const float* w_root0 = (const float*)d_in[2];
    const float* w_nbr0  = (const float*)d_in[3];
    const float* b0      = (const float*)d_in[4];
    const float* w_root1 = (const float*)d_in[5];
    const float* w_nbr1  = (const float*)d_in[6];
    const float* b1      = (const float*)d_in[7];
    const float* gamma0  = (const float*)d_in[8];
    const float* beta0   = (const float*)d_in[9];
    const float* gamma1  = (const float*)d_in[10];
    const float* beta1   = (const float*)d_in[11];
    const float* w_lin   = (const float*)d_in[12];
    const float* b_lin   = (const float*)d_in[13];
    float* out = (float*)d_out;

    const int n_nodes = in_sizes[0] / CIN;   // 100000
    const int n_edges = in_sizes[1] / 2;     // 1600000
    const int* src = ei;
    const int* dst = ei + n_edges;
    const int npad = (n_nodes + 63) & ~63;
    const int nbuck = (n_nodes + (1 << BSH) - 1) >> BSH;  // 196

    // ---- workspace layout ----
    char* ws = (char*)d_ws;
    unsigned short* ab0 = (unsigned short*)ws;                       // npad*128 bf16
    unsigned short* a1  = ab0 + (size_t)npad * 128;                  // npad*320 bf16
    unsigned short* wp0 = a1 + (size_t)npad * 320;                   // 16384
    unsigned short* wp1 = wp0 + 8 * 4 * 64 * 8;                      // 40960
    int*  bcur   = (int*)(wp1 + 8 * 10 * 64 * 8);                    // nbuck*CURPAD
    int*  rowptr = bcur + (size_t)nbuck * CURPAD;                    // n_nodes
    int*  deg    = rowptr + n_nodes;                                 // n_nodes
    unsigned int* bstage = (unsigned int*)(deg + n_nodes);           // nbuck*BCAP (also es)

    const int eblk = (n_edges + EPB - 1) / EPB;                      // 196
    const int cblk = (n_nodes * 16 + 255) / 256;
    const int wblk = (8 * 4 * 64 * 8 + 8 * 10 * 64 * 8 + 255) / 256;
    const int nblk64 = npad / 64;
    const int nblk16 = (n_nodes + 15) / 16;

    // ---- prep: 2-phase bucket scatter | x convert | weight pack ----
    hipMemsetAsync(bcur, 0, (size_t)nbuck * CURPAD * sizeof(int), stream);
    fused_prep<<<eblk + cblk + wblk, 256, 0, stream>>>(
        src, dst, x, w_root0, w_nbr0, w_root1, w_nbr1, w_lin,
        bcur, bstage, ab0, a1, wp0, wp1, n_nodes, n_edges, eblk, cblk);
    bucket_csr<<<nbuck, 256, 0, stream>>>(bstage, bcur, rowptr, deg, n_nodes);

    // ---- GraphConv 0 ----
    gather_c64<<<nblk16, 256, 0, stream>>>(ab0, rowptr, deg, bstage, n_nodes);
    conv0_mfma<<<nblk64, 256, 0, stream>>>(ab0, wp0, b0, gamma0, beta0, a1, n_nodes);

    // ---- GraphConv 1 + residual ----
    gather_c128<<<nblk16, 256, 0, stream>>>(a1, rowptr, deg, bstage, n_nodes);
    conv1_mfma<<<nblk64, 256, 0, stream>>>(a1, wp1, b1, b_lin, gamma1, beta1, out, n_nodes);
}